// Round 4
// baseline (232.506 us; speedup 1.0000x reference)
//
#include <hip/hip_runtime.h>
#include <cstdint>
#include <cmath>

// Problem constants (fixed by setup_inputs)
#define NROWS 32768
#define HD    1024
#define NMOT  128
#define NCLS  16
#define KSEL  32
#define EPSV  1e-4f

typedef __attribute__((ext_vector_type(4))) float  f32x4;
typedef __attribute__((ext_vector_type(8))) __bf16 bf16x8;
typedef __attribute__((ext_vector_type(4))) __bf16 bf16x4;
typedef unsigned long long u64;

// ---- workspace layout (in float slots) ----
// wsf[0..512)          : lossP[512] — per-GEMM-block loss partials
// wsf[512..640)        : mn[128]   — motif squared norms
// wsf[1024..66560)     : mvbf — mv converted to bf16 (128x1024)
// wsf[66560..197632)   : s1k[128][512] u64 — stage-1 top-32 keys
// wsf[197632..459776)  : cd[32768][8] — per-row dist to its 8 same-class motifs
#define WS_LP   0
#define WS_MN   512
#define WS_MVBF 1024
#define WS_S1K  66560
#define WS_CD   197632
#define CAPC    256     // per-(class,2048-row-chunk) candidate cap: mean 128, sigma 11

static __device__ __forceinline__ float dot4(float4 v) {
    return v.x * v.x + v.y * v.y + v.z * v.z + v.w * v.w;
}

static __device__ __forceinline__ bf16x4 cvt4(float4 v) {
    bf16x4 t;
    t[0] = (__bf16)v.x; t[1] = (__bf16)v.y; t[2] = (__bf16)v.z; t[3] = (__bf16)v.w;
    return t;
}

static __device__ __forceinline__ bf16x8 cvt8(float4 a, float4 b) {
    bf16x8 t;
    t[0] = (__bf16)a.x; t[1] = (__bf16)a.y; t[2] = (__bf16)a.z; t[3] = (__bf16)a.w;
    t[4] = (__bf16)b.x; t[5] = (__bf16)b.y; t[6] = (__bf16)b.z; t[7] = (__bf16)b.w;
    return t;
}

// async 16B global->LDS (DMA; LDS dest = wave-uniform base + lane*16)
static __device__ __forceinline__ void gl16(const void* g, void* l) {
    __builtin_amdgcn_global_load_lds(
        (const __attribute__((address_space(1))) void*)g,
        (__attribute__((address_space(3))) void*)l, 16, 0, 0);
}

// packed key: ascending u64 order == (value descending, index ascending)
static __device__ __forceinline__ u64 pack_key(float v, int idx) {
    unsigned int b = __float_as_uint(v);
    unsigned int mo = (b & 0x80000000u) ? ~b : (b | 0x80000000u); // ascending map
    unsigned int khi = ~mo;                                      // descending
    return ((u64)khi << 32) | (unsigned int)idx;
}

// ---------------------------------------------------------------------------
// Kernel 0: prep — mv -> bf16 copy + motif squared norms. 128 blocks.
// ---------------------------------------------------------------------------
__global__ __launch_bounds__(256) void prep_k(const float* __restrict__ mv,
                                              float* __restrict__ mn,
                                              __bf16* __restrict__ mvbf) {
    const int b = blockIdx.x;
    const int tid = threadIdx.x;
    const int k = tid * 4;               // 256 threads x 4 = 1024 = HD
    float4 v = *(const float4*)&mv[(size_t)b * HD + k];
    *(bf16x4*)&mvbf[(size_t)b * HD + k] = cvt4(v);
    float s = dot4(v);
#pragma unroll
    for (int o = 1; o < 64; o <<= 1) s += __shfl_xor(s, o, 64);
    __shared__ float red[4];
    if ((tid & 63) == 0) red[tid >> 6] = s;
    __syncthreads();
    if (tid == 0) mn[b] = red[0] + red[1] + red[2] + red[3];
}

// ---------------------------------------------------------------------------
// Kernel 1: streaming bf16-MFMA GEMM (z @ M^T), A direct-to-register.
//  - each wave owns 16 rows; A-fragment = 8 consecutive f32 per lane
//    (row = lane&15, k-chunk = (lane>>4)*8) loaded global->reg->cvt->MFMA.
//    No A LDS round-trip (each row consumed by exactly one wave).
//  - B (precomputed mvbf) staged via global_load_lds into a 4-deep LDS slab
//    ring, granule-swizzled so ds_read_b128 fragment reads are ~conflict-free.
//  - raw s_barrier + counted s_waitcnt vmcnt(4): A-ring (2 slabs ahead) and
//    B-DMA (2 slabs ahead) stay IN FLIGHT across barriers (never vmcnt(0)).
//  - epilogue fully in-register (shfl for ||z||^2 / y / loss).
// Tile: 64 rows x 128 cols, BK=32, grid 512 (2 blocks/CU).
// ---------------------------------------------------------------------------
#define BM 64
#define BK 32
#define NS (HD / BK)   // 32 k-slabs

__global__ __launch_bounds__(256, 2) void gemm_fused(
    const float* __restrict__ z, const __bf16* __restrict__ mvbf,
    const float* __restrict__ mn, float* __restrict__ cd,
    const int* __restrict__ y, float* __restrict__ lossP) {
    __shared__ __align__(16) __bf16 Bs[4][4096];  // 4 x 8KB k-slab ring
    __shared__ float redw[4];

    const int tid  = threadIdx.x;
    const int lane = tid & 63;
    const int wid  = tid >> 6;     // wave 0..3 owns rows wid*16 .. wid*16+15
    const int l15  = lane & 15;
    const int quad = lane >> 4;
    const int row0 = blockIdx.x * BM;
    const int myrow = row0 + wid * 16 + l15;

    // A source: row myrow, bytes quad*32 within each 128B k-slab row
    const float* zrow = z + (size_t)myrow * HD + quad * 8;

    // B DMA granule map: granule g holds B row r=g>>2, k-chunk q=(g&3)^((r>>1)&3)
    const int g1 = tid, g2 = tid + 256;
    const int r1 = g1 >> 2, r2 = g2 >> 2;
    const int q1 = (g1 & 3) ^ ((r1 >> 1) & 3);
    const int q2 = (g2 & 3) ^ ((r2 >> 1) & 3);
    const __bf16* bsrc1 = mvbf + r1 * HD + q1 * 8;
    const __bf16* bsrc2 = mvbf + r2 * HD + q2 * 8;
    char* bs = (char*)Bs;
    // B fragment read offset (swizzle matches write map; j*1024 added as imm)
    const int bofs = l15 * 64 + ((quad ^ ((l15 >> 1) & 3)) << 4);

    float mcv[8];
#pragma unroll
    for (int j = 0; j < 8; ++j) mcv[j] = mn[j * 16 + l15];
    const int yv = y[myrow];

    f32x4 acc[8];
#pragma unroll
    for (int j = 0; j < 8; ++j) acc[j] = (f32x4){0.f, 0.f, 0.f, 0.f};
    float zsq = 0.f;
    float4 ra[2][2];

    // ---- prologue: DMA slabs 0,1 -> bufs 0,1; A-ring slabs 0,1 ----
    gl16(bsrc1,      bs + 0 * 8192 + wid * 1024);
    gl16(bsrc2,      bs + 0 * 8192 + 4096 + wid * 1024);
    gl16(bsrc1 + BK, bs + 1 * 8192 + wid * 1024);
    gl16(bsrc2 + BK, bs + 1 * 8192 + 4096 + wid * 1024);
    ra[0][0] = *(const float4*)(zrow);
    ra[0][1] = *(const float4*)(zrow + 4);
    ra[1][0] = *(const float4*)(zrow + BK);
    ra[1][1] = *(const float4*)(zrow + BK + 4);
    __builtin_amdgcn_sched_barrier(0);
    asm volatile("s_waitcnt vmcnt(6)" ::: "memory");  // slab-0 DMA landed
    __builtin_amdgcn_s_barrier();
    asm volatile("" ::: "memory");
    __builtin_amdgcn_sched_barrier(0);

    // ---- main loop: slab kt reads buf kt&3; DMA + A-loads run 2 slabs ahead
    for (int it = 0; it < NS / 4; ++it) {
#pragma unroll
        for (int u = 0; u < 4; ++u) {
            const int kt = it * 4 + u;
            const int slot = u & 1;
            // B fragments for this slab
            bf16x8 bfr[8];
#pragma unroll
            for (int j = 0; j < 8; ++j)
                bfr[j] = *(const bf16x8*)(bs + u * 8192 + j * 1024 + bofs);
            // B DMA for slab kt+2 (into ring buf (u+2)&3)
            if (kt + 2 < NS) {
                char* d = bs + ((u + 2) & 3) * 8192 + wid * 1024;
                gl16(bsrc1 + (kt + 2) * BK, d);
                gl16(bsrc2 + (kt + 2) * BK, d + 4096);
            }
            // A: cvt slab kt fragment, accumulate ||z||^2, refill ring (kt+2)
            bf16x8 af = cvt8(ra[slot][0], ra[slot][1]);
            zsq += dot4(ra[slot][0]) + dot4(ra[slot][1]);
            if (kt + 2 < NS) {
                ra[slot][0] = *(const float4*)(zrow + (kt + 2) * BK);
                ra[slot][1] = *(const float4*)(zrow + (kt + 2) * BK + 4);
            }
            // MFMA: 16 rows x 128 cols, K=32
#pragma unroll
            for (int j = 0; j < 8; ++j)
                acc[j] = __builtin_amdgcn_mfma_f32_16x16x32_bf16(
                    af, bfr[j], acc[j], 0, 0, 0);
            // counted fence + raw barrier: keep 4 newest (DMA kt+2, A kt+2)
            if (kt + 2 < NS) {
                __builtin_amdgcn_sched_barrier(0);
                asm volatile("s_waitcnt vmcnt(4) lgkmcnt(0)" ::: "memory");
                __builtin_amdgcn_s_barrier();
                asm volatile("" ::: "memory");
                __builtin_amdgcn_sched_barrier(0);
            } else if (kt + 1 < NS) {   // kt == NS-2: drain DMA(NS-1), keep A(NS-1)
                __builtin_amdgcn_sched_barrier(0);
                asm volatile("s_waitcnt vmcnt(2) lgkmcnt(0)" ::: "memory");
                __builtin_amdgcn_s_barrier();
                asm volatile("" ::: "memory");
                __builtin_amdgcn_sched_barrier(0);
            }
        }
    }

    // ---- epilogue: in-register. reduce ||z||^2 over the 4 k-chunk lanes ----
    zsq += __shfl_xor(zsq, 16, 64);
    zsq += __shfl_xor(zsq, 32, 64);   // all lanes: ||z||^2 of row (wid*16+l15)

    float znv[4]; int rcls[4];
#pragma unroll
    for (int reg = 0; reg < 4; ++reg) {
        znv[reg]  = __shfl(zsq, quad * 4 + reg, 64);
        rcls[reg] = __shfl(yv,  quad * 4 + reg, 64);
    }
    float pm[4], ns[4];
#pragma unroll
    for (int reg = 0; reg < 4; ++reg) { pm[reg] = 0.f; ns[reg] = 0.f; }

    // C/D layout: col = lane&15 (within n-tile j), row = quad*4 + reg [verified]
#pragma unroll
    for (int j = 0; j < 8; ++j) {
        const int c = j * 16 + l15;
        const float mc = mcv[j];
        const int ccls = c >> 3;
#pragma unroll
        for (int reg = 0; reg < 4; ++reg) {
            float d = znv[reg] + mc - 2.f * acc[j][reg];
            float r = (d + 1.0f) * __builtin_amdgcn_rcpf(d + EPSV);
            float r2 = r * r;
            float s = r2 * r2 * r;   // ratio^5 == exp(log(ratio)/0.2)
            if (ccls == rcls[reg]) {
                pm[reg] = fmaxf(pm[reg], s);
                const int row = row0 + wid * 16 + quad * 4 + reg;
                cd[(size_t)row * 8 + (c & 7)] = d;
            } else {
                ns[reg] += s;
            }
        }
    }
    // reduce over the 16 column-lanes of each quad group
#pragma unroll
    for (int o = 1; o < 16; o <<= 1)
#pragma unroll
        for (int reg = 0; reg < 4; ++reg) {
            pm[reg] = fmaxf(pm[reg], __shfl_xor(pm[reg], o, 64));
            ns[reg] += __shfl_xor(ns[reg], o, 64);
        }
    float li = 0.f;
    if (l15 == 0) {
#pragma unroll
        for (int reg = 0; reg < 4; ++reg)
            li += logf((ns[reg] + pm[reg]) / pm[reg]);  // = -log(pos/(neg+pos))
    }
    li += __shfl_xor(li, 16, 64);
    li += __shfl_xor(li, 32, 64);
    if (lane == 0) redw[wid] = li;
    __syncthreads();
    if (tid == 0) lossP[blockIdx.x] = redw[0] + redw[1] + redw[2] + redw[3];
}

// ---------------------------------------------------------------------------
// Kernel 2: stage-1 top-32. One block per (motif, 2048-row chunk) = 2048
// blocks. Inline ballot-scan of y builds the candidate list (<=256), gathers
// cd, packs keys, bitonic-256 sorts (== value desc, idx asc), emits top-32.
// ---------------------------------------------------------------------------
__global__ __launch_bounds__(256) void sel1_k(const int* __restrict__ y,
                                              const float* __restrict__ cd,
                                              u64* __restrict__ s1k) {
    __shared__ u64 keys[256];
    __shared__ int clist[CAPC];
    __shared__ int cnt;

    const int bid = blockIdx.x;
    const int j = bid >> 4, chunk = bid & 15;
    const int cls = j >> 3, m8 = j & 7;
    const int tid = threadIdx.x;
    const int lane = tid & 63;

    if (tid == 0) cnt = 0;
    __syncthreads();
    const int base = chunk * 2048;
#pragma unroll
    for (int t = 0; t < 8; ++t) {
        const int i = base + t * 256 + tid;
        const bool pred = (y[i] == cls);
        const u64 m = __ballot(pred);
        int wbase = 0;
        if (lane == 0 && m) wbase = atomicAdd(&cnt, (int)__popcll(m));
        wbase = __shfl(wbase, 0, 64);
        if (pred) {
            const int p = wbase + (int)__popcll(m & ((1ull << lane) - 1ull));
            if (p < CAPC) clist[p] = i;
        }
    }
    __syncthreads();
    const int n = cnt < CAPC ? cnt : CAPC;

    u64 key = ~0ull;
    if (tid < n) {
        const int idx = clist[tid];
        key = pack_key(cd[(size_t)idx * 8 + m8], idx);
    }
    keys[tid] = key;
    __syncthreads();

    for (int k = 2; k <= 256; k <<= 1) {
        for (int jj = k >> 1; jj > 0; jj >>= 1) {
            if (tid < 128) {
                const int i  = ((tid & ~(jj - 1)) << 1) | (tid & (jj - 1));
                const int ix = i | jj;
                const u64 A = keys[i], B = keys[ix];
                const bool up = ((i & k) == 0);
                if ((A > B) == up) { keys[i] = B; keys[ix] = A; }
            }
            __syncthreads();
        }
    }
    if (tid < KSEL) s1k[(size_t)j * 512 + chunk * KSEL + tid] = keys[tid];
}

// ---------------------------------------------------------------------------
// Kernel 3: merge 16x32 stage-1 keys -> global top-32 (bitonic-512, redundant
// per column-quarter), gather-mean of selected z rows, tau-blend, write.
// 512 blocks: (motif j = b>>2, column quarter q = b&3). Block 0 also reduces
// the 512 loss partials -> out[0].
// ---------------------------------------------------------------------------
__global__ __launch_bounds__(256) void merge_k(
    const float* __restrict__ z, const float* __restrict__ mv,
    const u64* __restrict__ s1k, const float* __restrict__ lossP,
    float* __restrict__ out) {
    __shared__ u64 keys[512];
    __shared__ int sel[KSEL];
    __shared__ float redf[4];

    const int b = blockIdx.x;
    const int j = b >> 2, q = b & 3;
    const int tid = threadIdx.x;
    const int lane = tid & 63;
    const int wave = tid >> 6;

    if (b == 0) {
        float s = lossP[tid] + lossP[tid + 256];
#pragma unroll
        for (int o = 1; o < 64; o <<= 1) s += __shfl_xor(s, o, 64);
        if (lane == 0) redf[wave] = s;
        __syncthreads();
        if (tid == 0)
            out[0] = (redf[0] + redf[1] + redf[2] + redf[3]) * (1.0f / NROWS);
    }

    keys[tid]       = s1k[(size_t)j * 512 + tid];
    keys[tid + 256] = s1k[(size_t)j * 512 + 256 + tid];
    __syncthreads();

    for (int k = 2; k <= 512; k <<= 1) {
        for (int jj = k >> 1; jj > 0; jj >>= 1) {
            const int i  = ((tid & ~(jj - 1)) << 1) | (tid & (jj - 1));
            const int ix = i | jj;
            const u64 A = keys[i], B = keys[ix];
            const bool up = ((i & k) == 0);
            if ((A > B) == up) { keys[i] = B; keys[ix] = A; }
            __syncthreads();
        }
    }
    if (tid < KSEL) sel[tid] = (int)(keys[tid] & 0xFFFFFFFFu);
    __syncthreads();

    const int h = q * 256 + tid;
    float s = 0.f;
#pragma unroll 8
    for (int r = 0; r < KSEL; ++r) s += z[(size_t)sel[r] * HD + h];
    out[1 + (size_t)j * HD + h] =
        0.99f * mv[(size_t)j * HD + h] + 0.01f * (s * (1.0f / KSEL));
}

// ---------------------------------------------------------------------------
extern "C" void kernel_launch(void* const* d_in, const int* in_sizes, int n_in,
                              void* d_out, int out_size, void* d_ws, size_t ws_size,
                              hipStream_t stream) {
    const float* z  = (const float*)d_in[0];
    const float* mv = (const float*)d_in[1];
    const int*   y  = (const int*)d_in[2];
    float* out = (float*)d_out;
    float* wsf = (float*)d_ws;
    float*  lossP = wsf + WS_LP;
    float*  mn    = wsf + WS_MN;
    __bf16* mvbf  = (__bf16*)(wsf + WS_MVBF);
    u64*    s1k   = (u64*)(wsf + WS_S1K);
    float*  cd    = wsf + WS_CD;

    hipLaunchKernelGGL(prep_k,     dim3(NMOT),      dim3(256), 0, stream,
                       mv, mn, mvbf);
    hipLaunchKernelGGL(gemm_fused, dim3(NROWS / BM), dim3(256), 0, stream,
                       z, mvbf, mn, cd, y, lossP);
    hipLaunchKernelGGL(sel1_k,     dim3(NMOT * 16), dim3(256), 0, stream,
                       y, cd, s1k);
    hipLaunchKernelGGL(merge_k,    dim3(NMOT * 4),  dim3(256), 0, stream,
                       z, mv, s1k, lossP, out);
}